// Round 3
// baseline (858.261 us; speedup 1.0000x reference)
//
#include <hip/hip_runtime.h>
#include <cstdint>

// SparseMLP: out = relu(relu(x@W1^T+b1)@W2^T+b2)@W3^T+b3
// M = N = K = 4096 per layer. fp32 in/out; fp16 MFMA internally.
//
// R3 changes vs R2 (691 us total; 3x168us GEMM + ~186us converts/gaps):
//  - Zero convert kernels. GEMM is templated on operand dtype and stages
//    fp32 operands directly via global_load_lds (16KB tile, 4 rounds),
//    converting f32->f16 at fragment-read time (2x ds_read_b128 + cvt).
//  - fp32 LDS swizzle: row = 128B = one full 32-bank line, so LDS slot l
//    of row r holds global chunk l ^ (r&7); reader slot (2kq+h)^(l16&7)
//    -> 8 slots x 2 lanes = 2-way aliasing = free (m136).
//  - __launch_bounds__(256,3): R2 only achieved 3 blocks/CU anyway; the
//    f32 paths need >64 arch VGPRs (staging ptrs + cvt temps) and (256,4)
//    would force spills.

#define MATN 4096

typedef _Float16 half8 __attribute__((ext_vector_type(8)));
typedef float f32x4 __attribute__((ext_vector_type(4)));

// async global->LDS, 16B/lane. LDS dest = wave-uniform base + lane*16.
__device__ __forceinline__ void glds16(const void* g, void* l) {
    __builtin_amdgcn_global_load_lds(
        (const __attribute__((address_space(1))) char*)(uintptr_t)g,
        (__attribute__((address_space(3))) char*)(uintptr_t)l,
        16, 0, 0);
}

// C[m][n] = sum_k A[m][k]*B[n][k] + bias[n] (optional ReLU).
// A: [4096][4096] AT row-major (K-contig), B: [4096][4096] BT row-major
// (B^T input, K-contig). AT/BT in {_Float16, float}; MFMA runs fp16.
// 128x128 tile, BK=32, 2x2 waves x 4x4 MFMA(16x16x32) per wave.
template <bool RELU, typename AT, typename BT, typename OutT>
__global__ __launch_bounds__(256, 3)
void gemm_bt(const AT* __restrict__ A, const BT* __restrict__ B,
             const float* __restrict__ bias, OutT* __restrict__ C) {
    constexpr int ASZ = (int)sizeof(AT);   // 2 or 4
    constexpr int BSZ = (int)sizeof(BT);
    constexpr int AR  = ASZ == 2 ? 2 : 4;  // 4KB staging rounds per tile
    constexpr int BR  = BSZ == 2 ? 2 : 4;

    __shared__ char smem[(ASZ + BSZ) * 4096];  // A tile then B tile

    const int tid  = threadIdx.x;
    const int lane = tid & 63;
    const int w    = tid >> 6;   // 4 waves
    const int wm   = w >> 1;     // 2x2 wave grid over 128x128
    const int wn   = w & 1;
    const int l16  = lane & 15;
    const int kq   = lane >> 4;  // 0..3 (k-quad)

    const int tileM = blockIdx.y * 128;
    const int tileN = blockIdx.x * 128;

    f32x4 acc[4][4] = {};

    // ---- staging pointers (XOR chunk swizzle; global_load_lds writes to
    // wave-uniform base + lane*16, flat lane order, so we permute which
    // global 16B k-chunk lands in each LDS slot and invert at read time).
    const AT* Ap[AR];
    if constexpr (ASZ == 2) {
        const int r = tid >> 2;                       // 0..63
        const int g = (tid & 3) ^ ((tid >> 3) & 3);   // slot ^ ((r>>1)&3)
        const AT* p = A + (size_t)(tileM + r) * MATN + g * 8;
#pragma unroll
        for (int c = 0; c < AR; ++c) Ap[c] = p + (size_t)(64 * c) * MATN;
    } else {
        const int r = tid >> 3;                       // 0..31
        const int g = (tid & 7) ^ ((tid >> 3) & 7);   // slot ^ (r&7)
        const AT* p = A + (size_t)(tileM + r) * MATN + g * 4;
#pragma unroll
        for (int c = 0; c < AR; ++c) Ap[c] = p + (size_t)(32 * c) * MATN;
    }
    const BT* Bp[BR];
    if constexpr (BSZ == 2) {
        const int r = tid >> 2;
        const int g = (tid & 3) ^ ((tid >> 3) & 3);
        const BT* p = B + (size_t)(tileN + r) * MATN + g * 8;
#pragma unroll
        for (int c = 0; c < BR; ++c) Bp[c] = p + (size_t)(64 * c) * MATN;
    } else {
        const int r = tid >> 3;
        const int g = (tid & 7) ^ ((tid >> 3) & 7);
        const BT* p = B + (size_t)(tileN + r) * MATN + g * 4;
#pragma unroll
        for (int c = 0; c < BR; ++c) Bp[c] = p + (size_t)(32 * c) * MATN;
    }

    char* sAl = smem + w * 1024;              // wave-uniform LDS bases
    char* sBl = smem + ASZ * 4096 + w * 1024;

    for (int k0 = 0; k0 < MATN / 32; ++k0) {
#pragma unroll
        for (int c = 0; c < AR; ++c) { glds16(Ap[c], sAl + c * 4096); Ap[c] += 32; }
#pragma unroll
        for (int c = 0; c < BR; ++c) { glds16(Bp[c], sBl + c * 4096); Bp[c] += 32; }
        __syncthreads();

        half8 af[4], bf[4];
        if constexpr (ASZ == 2) {
            const _Float16* rA = (const _Float16*)smem
                + (wm * 64 + l16) * 32 + (kq ^ ((l16 >> 1) & 3)) * 8;
#pragma unroll
            for (int mi = 0; mi < 4; ++mi)
                af[mi] = *(const half8*)(rA + mi * 512);
        } else {
            const float* rA = (const float*)smem + (wm * 64 + l16) * 32;
            const int s0 = (2 * kq) ^ (l16 & 7);
            const int s1 = (2 * kq + 1) ^ (l16 & 7);
#pragma unroll
            for (int mi = 0; mi < 4; ++mi) {
                float4 lo = *(const float4*)(rA + mi * 512 + s0 * 4);
                float4 hi = *(const float4*)(rA + mi * 512 + s1 * 4);
                half8 f;
                f[0] = (_Float16)lo.x; f[1] = (_Float16)lo.y;
                f[2] = (_Float16)lo.z; f[3] = (_Float16)lo.w;
                f[4] = (_Float16)hi.x; f[5] = (_Float16)hi.y;
                f[6] = (_Float16)hi.z; f[7] = (_Float16)hi.w;
                af[mi] = f;
            }
        }
        if constexpr (BSZ == 2) {
            const _Float16* rB = (const _Float16*)(smem + ASZ * 4096)
                + (wn * 64 + l16) * 32 + (kq ^ ((l16 >> 1) & 3)) * 8;
#pragma unroll
            for (int ni = 0; ni < 4; ++ni)
                bf[ni] = *(const half8*)(rB + ni * 512);
        } else {
            const float* rB = (const float*)(smem + ASZ * 4096)
                + (wn * 64 + l16) * 32;
            const int s0 = (2 * kq) ^ (l16 & 7);
            const int s1 = (2 * kq + 1) ^ (l16 & 7);
#pragma unroll
            for (int ni = 0; ni < 4; ++ni) {
                float4 lo = *(const float4*)(rB + ni * 512 + s0 * 4);
                float4 hi = *(const float4*)(rB + ni * 512 + s1 * 4);
                half8 f;
                f[0] = (_Float16)lo.x; f[1] = (_Float16)lo.y;
                f[2] = (_Float16)lo.z; f[3] = (_Float16)lo.w;
                f[4] = (_Float16)hi.x; f[5] = (_Float16)hi.y;
                f[6] = (_Float16)hi.z; f[7] = (_Float16)hi.w;
                bf[ni] = f;
            }
        }

#pragma unroll
        for (int mi = 0; mi < 4; ++mi)
#pragma unroll
            for (int ni = 0; ni < 4; ++ni)
                acc[mi][ni] = __builtin_amdgcn_mfma_f32_16x16x32_f16(
                    af[mi], bf[ni], acc[mi][ni], 0, 0, 0);
        __syncthreads();
    }

    // epilogue: C/D layout col = lane&15, row = (lane>>4)*4 + reg (m89)
#pragma unroll
    for (int ni = 0; ni < 4; ++ni) {
        const int gn = tileN + wn * 64 + ni * 16 + l16;
        const float bv = bias[gn];
#pragma unroll
        for (int mi = 0; mi < 4; ++mi) {
            const int gm = tileM + wm * 64 + mi * 16 + kq * 4;
#pragma unroll
            for (int r = 0; r < 4; ++r) {
                float v = acc[mi][ni][r] + bv;
                if (RELU) v = v > 0.f ? v : 0.f;
                C[(size_t)(gm + r) * MATN + gn] = (OutT)v;
            }
        }
    }
}

extern "C" void kernel_launch(void* const* d_in, const int* in_sizes, int n_in,
                              void* d_out, int out_size, void* d_ws, size_t ws_size,
                              hipStream_t stream) {
    const float* x  = (const float*)d_in[0];
    const float* W1 = (const float*)d_in[1];
    const float* b1 = (const float*)d_in[2];
    const float* W2 = (const float*)d_in[3];
    const float* b2 = (const float*)d_in[4];
    const float* W3 = (const float*)d_in[5];
    const float* b3 = (const float*)d_in[6];
    float* out = (float*)d_out;

    const size_t MAT = (size_t)MATN * MATN;
    _Float16* h1 = (_Float16*)d_ws;                     // 32MB
    _Float16* h2 = (_Float16*)((char*)d_ws + MAT * 2);  // 32MB

    dim3 ggrid(MATN / 128, MATN / 128);  // 32x32

    gemm_bt<true,  float,    float, _Float16><<<ggrid, 256, 0, stream>>>(x,  W1, b1, h1);
    gemm_bt<true,  _Float16, float, _Float16><<<ggrid, 256, 0, stream>>>(h1, W2, b2, h2);
    gemm_bt<false, _Float16, float, float   ><<<ggrid, 256, 0, stream>>>(h2, W3, b3, out);
}

// Round 4
// 594.746 us; speedup vs baseline: 1.4431x; 1.4431x over previous
//
#include <hip/hip_runtime.h>
#include <cstdint>

// SparseMLP: out = relu(relu(x@W1^T+b1)@W2^T+b2)@W3^T+b3
// M = N = K = 4096 per layer. fp32 in/out; fp16 MFMA internally.
//
// R4 vs R3 (858us, regression): revert to all-fp16 GEMM operands (R3's
// stage-fp32-convert-at-read cost +87us/side: 2x redundant cvt + 2x ds_read
// + bank conflicts). vs R2 (691us):
//  - converts consolidated 4 launches -> 3 (cvt2 does x+W1 via gridDim.y),
//    grid-stride fat blocks (R2's 8KB/block converts were launch-bound).
//  - BK=64 K-loop: halves barrier-drain count (the m97-structure ~20%
//    stall). LDS 2x16KB=32KB. Swizzle re-derived for 128B rows at
//    quarter-wave granularity: slot l of row r holds chunk l^(r&7);
//    reader slot (khalf*4+kq)^(l16&7) -> 16 lanes over 8 slots = 2-way = free.

#define MATN 4096

typedef _Float16 half8 __attribute__((ext_vector_type(8)));
typedef float f32x4 __attribute__((ext_vector_type(4)));

// async global->LDS, 16B/lane. LDS dest = wave-uniform base + lane*16.
__device__ __forceinline__ void glds16(const void* g, void* l) {
    __builtin_amdgcn_global_load_lds(
        (const __attribute__((address_space(1))) char*)(uintptr_t)g,
        (__attribute__((address_space(3))) char*)(uintptr_t)l,
        16, 0, 0);
}

__device__ __forceinline__ void cvt_body(const float* __restrict__ in,
                                         _Float16* __restrict__ out, int n8) {
    for (int g = blockIdx.x * 256 + threadIdx.x; g < n8; g += gridDim.x * 256) {
        size_t i = (size_t)g * 8;
        float4 a = *(const float4*)(in + i);
        float4 b = *(const float4*)(in + i + 4);
        half8 o;
        o[0] = (_Float16)a.x; o[1] = (_Float16)a.y;
        o[2] = (_Float16)a.z; o[3] = (_Float16)a.w;
        o[4] = (_Float16)b.x; o[5] = (_Float16)b.y;
        o[6] = (_Float16)b.z; o[7] = (_Float16)b.w;
        *(half8*)(out + i) = o;
    }
}

__global__ __launch_bounds__(256)
void cvt_f16(const float* __restrict__ in, _Float16* __restrict__ out, int n8) {
    cvt_body(in, out, n8);
}

// two tensors in one launch (gridDim.y = 2)
__global__ __launch_bounds__(256)
void cvt_f16_2(const float* __restrict__ i0, _Float16* __restrict__ o0,
               const float* __restrict__ i1, _Float16* __restrict__ o1, int n8) {
    cvt_body(blockIdx.y ? i1 : i0, blockIdx.y ? o1 : o0, n8);
}

// C[m][n] = sum_k A[m][k]*B[n][k] + bias[n] (optional ReLU).
// A,B: [4096][4096] f16 row-major (K-contig). 128x128 tile, BK=64,
// 2x2 waves x 4x4 MFMA(16x16x32) per wave, 2 k-halves per stage.
template <bool RELU, typename OutT>
__global__ __launch_bounds__(256, 4)
void gemm_bt(const _Float16* __restrict__ A, const _Float16* __restrict__ B,
             const float* __restrict__ bias, OutT* __restrict__ C) {
    __shared__ _Float16 sA[128 * 64];  // 16 KB, 128B rows, XOR-swizzled chunks
    __shared__ _Float16 sB[128 * 64];

    const int tid  = threadIdx.x;
    const int lane = tid & 63;
    const int w    = tid >> 6;   // 4 waves
    const int wm   = w >> 1;     // 2x2 wave grid over 128x128
    const int wn   = w & 1;
    const int l16  = lane & 15;
    const int kq   = lane >> 4;  // 0..3

    const int tileM = blockIdx.y * 128;
    const int tileN = blockIdx.x * 128;

    f32x4 acc[4][4] = {};

    // staging: thread t -> row_in = t>>3 (0..31), slot = t&7.
    // LDS slot s of row r holds global 16B chunk s ^ (r&7), so thread t
    // fetches chunk (t&7)^(row_in&7). Rows advance 32/round (32%8==0, so
    // the per-thread swizzle term is round-invariant).
    const int rin = tid >> 3;
    const int gch = (tid & 7) ^ (rin & 7);
    const _Float16* Ap = A + (size_t)(tileM + rin) * MATN + gch * 8;
    const _Float16* Bp = B + (size_t)(tileN + rin) * MATN + gch * 8;
    const size_t rstep = (size_t)32 * MATN;  // rows between staging rounds

    char* sAl = (char*)sA + w * 1024;  // wave-uniform LDS bases
    char* sBl = (char*)sB + w * 1024;

    // fragment read bases (khalf 0/1): row = wm*64+mi*16+l16 (row&7 = l16&7),
    // wanted chunk = khalf*4+kq -> slot = (khalf*4+kq)^(l16&7).
    const int sl0 = kq ^ (l16 & 7);
    const int sl1 = sl0 ^ 4;
    const _Float16* rA0 = sA + (wm * 64 + l16) * 64 + sl0 * 8;
    const _Float16* rA1 = sA + (wm * 64 + l16) * 64 + sl1 * 8;
    const _Float16* rB0 = sB + (wn * 64 + l16) * 64 + sl0 * 8;
    const _Float16* rB1 = sB + (wn * 64 + l16) * 64 + sl1 * 8;

    for (int k0 = 0; k0 < MATN; k0 += 64) {
#pragma unroll
        for (int c = 0; c < 4; ++c) glds16(Ap + c * rstep, sAl + c * 4096);
#pragma unroll
        for (int c = 0; c < 4; ++c) glds16(Bp + c * rstep, sBl + c * 4096);
        Ap += 64; Bp += 64;
        __syncthreads();

        half8 af[4], bf[4];
        // k-half 0
#pragma unroll
        for (int mi = 0; mi < 4; ++mi) af[mi] = *(const half8*)(rA0 + mi * 1024);
#pragma unroll
        for (int ni = 0; ni < 4; ++ni) bf[ni] = *(const half8*)(rB0 + ni * 1024);
#pragma unroll
        for (int mi = 0; mi < 4; ++mi)
#pragma unroll
            for (int ni = 0; ni < 4; ++ni)
                acc[mi][ni] = __builtin_amdgcn_mfma_f32_16x16x32_f16(
                    af[mi], bf[ni], acc[mi][ni], 0, 0, 0);
        // k-half 1
#pragma unroll
        for (int mi = 0; mi < 4; ++mi) af[mi] = *(const half8*)(rA1 + mi * 1024);
#pragma unroll
        for (int ni = 0; ni < 4; ++ni) bf[ni] = *(const half8*)(rB1 + ni * 1024);
#pragma unroll
        for (int mi = 0; mi < 4; ++mi)
#pragma unroll
            for (int ni = 0; ni < 4; ++ni)
                acc[mi][ni] = __builtin_amdgcn_mfma_f32_16x16x32_f16(
                    af[mi], bf[ni], acc[mi][ni], 0, 0, 0);
        __syncthreads();
    }

    // epilogue: C/D layout col = lane&15, row = (lane>>4)*4 + reg (m89)
#pragma unroll
    for (int ni = 0; ni < 4; ++ni) {
        const int gn = tileN + wn * 64 + ni * 16 + l16;
        const float bv = bias[gn];
#pragma unroll
        for (int mi = 0; mi < 4; ++mi) {
            const int gm = tileM + wm * 64 + mi * 16 + kq * 4;
#pragma unroll
            for (int r = 0; r < 4; ++r) {
                float v = acc[mi][ni][r] + bv;
                if (RELU) v = v > 0.f ? v : 0.f;
                C[(size_t)(gm + r) * MATN + gn] = (OutT)v;
            }
        }
    }
}

extern "C" void kernel_launch(void* const* d_in, const int* in_sizes, int n_in,
                              void* d_out, int out_size, void* d_ws, size_t ws_size,
                              hipStream_t stream) {
    const float* x  = (const float*)d_in[0];
    const float* W1 = (const float*)d_in[1];
    const float* b1 = (const float*)d_in[2];
    const float* W2 = (const float*)d_in[3];
    const float* b2 = (const float*)d_in[4];
    const float* W3 = (const float*)d_in[5];
    const float* b3 = (const float*)d_in[6];
    float* out = (float*)d_out;

    const size_t MAT = (size_t)MATN * MATN;
    _Float16* xb = (_Float16*)d_ws;                     // 32MB (reused as h2)
    _Float16* wb = (_Float16*)((char*)d_ws + MAT * 2);  // 32MB (per-layer W)
    _Float16* h1 = (_Float16*)((char*)d_ws + MAT * 4);  // 32MB
    _Float16* h2 = xb;

    const int n8 = (int)(MAT / 8);
    dim3 ggrid(MATN / 128, MATN / 128);  // 32x32

    cvt_f16_2<<<dim3(2048, 2), 256, 0, stream>>>(x, xb, W1, wb, n8);
    gemm_bt<true, _Float16><<<ggrid, 256, 0, stream>>>(xb, wb, b1, h1);

    cvt_f16<<<2048, 256, 0, stream>>>(W2, wb, n8);
    gemm_bt<true, _Float16><<<ggrid, 256, 0, stream>>>(h1, wb, b2, h2);

    cvt_f16<<<2048, 256, 0, stream>>>(W3, wb, n8);
    gemm_bt<false, float><<<ggrid, 256, 0, stream>>>(h2, wb, b3, out);
}